// Round 6
// baseline (801.453 us; speedup 1.0000x reference)
//
#include <hip/hip_runtime.h>

// Covariance: B=8, T=512, F=513, M=8, AVERAGE=True
constexpr int kB  = 8;
constexpr int kT  = 512;
constexpr int kF  = 513;
constexpr int kM  = 8;
constexpr int kNP = 36;        // M*(M+1)/2 pairs
constexpr int kC  = 2 * kNP;   // 72 floats per (b,t,f)
constexpr int kFT = 64;        // f-tile width (= wave)
constexpr int kNFT = 9;        // ceil(F/64)
constexpr int kNTC = 8;        // t-chunks (R1 best-known)
constexpr int kTC = kT / kNTC; // 64 t per chunk
constexpr int kLDP = kC + 1;   // LDS row pad
constexpr int kS4 = kF * kC / 4;          // float4s per (b,t) slice = 9234
constexpr unsigned kBreg4 = (unsigned)kT * kS4;  // float4s per b = 4,727,808

typedef float f32x4 __attribute__((ext_vector_type(4)));  // nt-store-compatible

// Stage 1: EXACT R1 form (best measured). Block per (b, f-tile, t-chunk).
// Lane = f (4KB contiguous per wave read). Wave w: t = t0+w, step 4, 16 iters,
// unroll 2 -> 8 loads in flight, 4 waves on adjacent t-rows (DRAM row locality).
__global__ __launch_bounds__(256) void cov_partial(const float* __restrict__ in,
                                                   float* __restrict__ out) {
  const int bx = blockIdx.x;
  const int b  = bx / (kNFT * kNTC);
  const int r  = bx - b * (kNFT * kNTC);
  const int ft = r / kNTC;
  const int tc = r - ft * kNTC;
  const int tid  = threadIdx.x;
  const int wave = tid >> 6;
  const int lane = tid & 63;
  const int f = ft * kFT + lane;

  float accR[kNP], accI[kNP];
#pragma unroll
  for (int p = 0; p < kNP; ++p) { accR[p] = 0.0f; accI[p] = 0.0f; }

  if (f < kF) {
    const int t0 = tc * kTC + wave;
    const float* base = in + ((size_t)(b * kT + t0) * kF + f) * (2 * kM);
    const size_t tstep = (size_t)4 * kF * (2 * kM);   // advance 4 t's
#pragma unroll 2
    for (int it = 0; it < kTC / 4; ++it) {
      const float* ptr = base + it * tstep;
      const float4 r0 = *(const float4*)(ptr + 0);
      const float4 r1 = *(const float4*)(ptr + 4);
      const float4 i0 = *(const float4*)(ptr + 8);
      const float4 i1 = *(const float4*)(ptr + 12);
      const float re[kM] = {r0.x, r0.y, r0.z, r0.w, r1.x, r1.y, r1.z, r1.w};
      const float im[kM] = {i0.x, i0.y, i0.z, i0.w, i1.x, i1.y, i1.z, i1.w};
      int p = 0;
#pragma unroll
      for (int i = 0; i < kM; ++i) {
#pragma unroll
        for (int j = i; j < kM; ++j) {
          accR[p] += re[i] * re[j] + im[i] * im[j];
          accI[p] += re[i] * im[j] - im[i] * re[j];
          ++p;
        }
      }
    }
  }

  __shared__ float buf[2][kFT * kLDP];
  float* my = buf[wave & 1] + lane * kLDP;
  if (wave < 2) {
#pragma unroll
    for (int p = 0; p < kNP; ++p) { my[p] = accR[p]; my[kNP + p] = accI[p]; }
  }
  __syncthreads();
  if (wave >= 2) {
#pragma unroll
    for (int p = 0; p < kNP; ++p) { my[p] += accR[p]; my[kNP + p] += accI[p]; }
  }
  __syncthreads();

  const int nf = min(kFT, kF - ft * kFT);
  float* dst = out + ((size_t)(b * kT + (1 + tc)) * kF + ft * kFT) * kC;
  const int n = nf * kC;
  for (int e = tid; e < n; e += 256) {
    const int l = (unsigned)e / (unsigned)kC;
    const int p = e - l * kC;
    dst[e] = buf[0][l * kLDP + p] + buf[1][l * kLDP + p];
  }
}

// Stage 2: sum the 8 partial slices (t=1..8), scale, write t=0 slice.
__global__ __launch_bounds__(256) void cov_combine(float4* __restrict__ out) {
  const int total4 = kB * kS4;                    // 73,872
  const int idx = blockIdx.x * 256 + threadIdx.x;
  if (idx >= total4) return;
  const int b = (unsigned)idx / (unsigned)kS4;
  const int fr4 = idx - b * kS4;
  const size_t bbase = (size_t)b * kBreg4;
  float4 s = make_float4(0.f, 0.f, 0.f, 0.f);
#pragma unroll
  for (int k = 0; k < kNTC; ++k) {
    const float4 v = out[bbase + (size_t)(1 + k) * kS4 + fr4];
    s.x += v.x; s.y += v.y; s.z += v.z; s.w += v.w;
  }
  const float sc = 1.0f / kT;
  s.x *= sc; s.y *= sc; s.z *= sc; s.w *= sc;
  out[bbase + fr4] = s;
}

// Stage 3: broadcast, PURELY LINEAR global write order (measured fastest),
// 64B per thread, NONTEMPORAL stores (no L2 write-allocate -> mean slice
// stays L2-resident, write path unpolluted).
__global__ __launch_bounds__(256) void cov_bcast(float* __restrict__ outf) {
  const f32x4* src4 = (const f32x4*)outf;
  f32x4* out4 = (f32x4*)outf;
  // total float4 = 37,822,464 = 9,455,616 threads * 4; grid covers exactly.
  const unsigned t4 = (blockIdx.x * 256u + threadIdx.x) * 4u;  // first float4
  const unsigned b   = t4 / kBreg4;            // kBreg4 divisible by 4
  const unsigned off = t4 - b * kBreg4;
  const unsigned fr  = off % (unsigned)kS4;    // position within mean slice
  const f32x4* src = src4 + (size_t)b * kBreg4;  // t=0 slice of this b
  unsigned f0 = fr;
  unsigned f1 = fr + 1; if (f1 >= (unsigned)kS4) f1 -= kS4;
  unsigned f2 = fr + 2; if (f2 >= (unsigned)kS4) f2 -= kS4;
  unsigned f3 = fr + 3; if (f3 >= (unsigned)kS4) f3 -= kS4;
  const f32x4 v0 = src[f0];
  const f32x4 v1 = src[f1];
  const f32x4 v2 = src[f2];
  const f32x4 v3 = src[f3];
  f32x4* dst = out4 + t4;
  __builtin_nontemporal_store(v0, dst + 0);   // t=0 region: value-identical
  __builtin_nontemporal_store(v1, dst + 1);   // self-copy (benign)
  __builtin_nontemporal_store(v2, dst + 2);
  __builtin_nontemporal_store(v3, dst + 3);
}

extern "C" void kernel_launch(void* const* d_in, const int* in_sizes, int n_in,
                              void* d_out, int out_size, void* d_ws, size_t ws_size,
                              hipStream_t stream) {
  const float* in = (const float*)d_in[0];
  float* out = (float*)d_out;

  cov_partial<<<dim3(kB * kNFT * kNTC), dim3(256), 0, stream>>>(in, out);

  const int total4 = kB * kS4;
  cov_combine<<<dim3((total4 + 255) / 256), dim3(256), 0, stream>>>((float4*)out);

  const unsigned nthreads = ((unsigned)kB * kBreg4) / 4u;   // 9,455,616
  cov_bcast<<<dim3(nthreads / 256u), dim3(256), 0, stream>>>(out);
}

// Round 7
// 149.726 us; speedup vs baseline: 5.3528x; 5.3528x over previous
//
#include <hip/hip_runtime.h>

// Covariance: B=8, T=512, F=513, M=8, AVERAGE=True
constexpr int kB  = 8;
constexpr int kT  = 512;
constexpr int kF  = 513;
constexpr int kM  = 8;
constexpr int kNP = 36;        // M*(M+1)/2 pairs
constexpr int kC  = 2 * kNP;   // 72 floats per (b,t,f)
constexpr int kFT = 64;        // f-tile width (= wave)
constexpr int kNFT = 9;        // ceil(F/64)
constexpr int kNTC = 16;       // t-chunks (1152 blocks = 4.5/CU)
constexpr int kTC = kT / kNTC; // 32 t per chunk
constexpr int kLDP = kC + 1;   // LDS row pad
constexpr int kS4 = kF * kC / 4;          // float4s per (b,t) slice = 9234
constexpr unsigned kBreg4 = (unsigned)kT * kS4;  // float4s per b = 4,727,808

// Stage 1: R1's exact access pattern (measured best): lane = f (4KB contiguous
// per wave read), wave w on t-row t0+w, step 4 (adjacent rows in flight =
// DRAM row locality), unroll 2 = 8 loads outstanding. Only change vs R1:
// half-size t-chunks -> 1152 blocks for read-latency hiding.
__global__ __launch_bounds__(256) void cov_partial(const float* __restrict__ in,
                                                   float* __restrict__ out) {
  const int bx = blockIdx.x;
  const int b  = bx / (kNFT * kNTC);
  const int r  = bx - b * (kNFT * kNTC);
  const int ft = r / kNTC;
  const int tc = r - ft * kNTC;
  const int tid  = threadIdx.x;
  const int wave = tid >> 6;
  const int lane = tid & 63;
  const int f = ft * kFT + lane;

  float accR[kNP], accI[kNP];
#pragma unroll
  for (int p = 0; p < kNP; ++p) { accR[p] = 0.0f; accI[p] = 0.0f; }

  if (f < kF) {
    const int t0 = tc * kTC + wave;
    const float* base = in + ((size_t)(b * kT + t0) * kF + f) * (2 * kM);
    const size_t tstep = (size_t)4 * kF * (2 * kM);   // advance 4 t's
#pragma unroll 2
    for (int it = 0; it < kTC / 4; ++it) {
      const float* ptr = base + it * tstep;
      const float4 r0 = *(const float4*)(ptr + 0);
      const float4 r1 = *(const float4*)(ptr + 4);
      const float4 i0 = *(const float4*)(ptr + 8);
      const float4 i1 = *(const float4*)(ptr + 12);
      const float re[kM] = {r0.x, r0.y, r0.z, r0.w, r1.x, r1.y, r1.z, r1.w};
      const float im[kM] = {i0.x, i0.y, i0.z, i0.w, i1.x, i1.y, i1.z, i1.w};
      int p = 0;
#pragma unroll
      for (int i = 0; i < kM; ++i) {
#pragma unroll
        for (int j = i; j < kM; ++j) {
          accR[p] += re[i] * re[j] + im[i] * im[j];
          accI[p] += re[i] * im[j] - im[i] * re[j];
          ++p;
        }
      }
    }
  }

  __shared__ float buf[2][kFT * kLDP];
  float* my = buf[wave & 1] + lane * kLDP;
  if (wave < 2) {
#pragma unroll
    for (int p = 0; p < kNP; ++p) { my[p] = accR[p]; my[kNP + p] = accI[p]; }
  }
  __syncthreads();
  if (wave >= 2) {
#pragma unroll
    for (int p = 0; p < kNP; ++p) { my[p] += accR[p]; my[kNP + p] += accI[p]; }
  }
  __syncthreads();

  const int nf = min(kFT, kF - ft * kFT);
  float* dst = out + ((size_t)(b * kT + (1 + tc)) * kF + ft * kFT) * kC;
  const int n = nf * kC;
  for (int e = tid; e < n; e += 256) {
    const int l = (unsigned)e / (unsigned)kC;
    const int p = e - l * kC;
    dst[e] = buf[0][l * kLDP + p] + buf[1][l * kLDP + p];
  }
}

// Stage 2: sum the 16 partial slices (t=1..16), scale, write t=0 slice.
__global__ __launch_bounds__(256) void cov_combine(float4* __restrict__ out) {
  const int total4 = kB * kS4;                    // 73,872
  const int idx = blockIdx.x * 256 + threadIdx.x;
  if (idx >= total4) return;
  const int b = (unsigned)idx / (unsigned)kS4;
  const int fr4 = idx - b * kS4;
  const size_t bbase = (size_t)b * kBreg4;
  float4 s = make_float4(0.f, 0.f, 0.f, 0.f);
#pragma unroll
  for (int k = 0; k < kNTC; ++k) {
    const float4 v = out[bbase + (size_t)(1 + k) * kS4 + fr4];
    s.x += v.x; s.y += v.y; s.z += v.z; s.w += v.w;
  }
  const float sc = 1.0f / kT;
  s.x *= sc; s.y *= sc; s.z *= sc; s.w *= sc;
  out[bbase + fr4] = s;
}

// Stage 3: broadcast t=0 slice to all t — EXACT R1 form (measured fastest):
// purely linear write order, one thread per output float4, NORMAL stores
// (L2 write-allocate/combining is the fast path on gfx950; nt-stores caused
// 2.7x write + 4.9GB RMW-fetch amplification in R6).
__global__ __launch_bounds__(256) void cov_bcast(float4* __restrict__ out) {
  const unsigned total4 = (unsigned)kB * kT * kF * (kC / 4);  // 37,822,464
  const unsigned idx = blockIdx.x * 256u + threadIdx.x;
  if (idx >= total4) return;
  const unsigned g = idx / (kC / 4);          // (b*T + t)*F + f
  const unsigned r = idx - g * (kC / 4);
  const unsigned b = g / (unsigned)(kT * kF);
  const unsigned f = g % (unsigned)kF;
  const unsigned src = (b * (unsigned)(kT * kF) + f) * (kC / 4) + r;
  out[idx] = out[src];   // t=0 is a value-identical self-copy
}

extern "C" void kernel_launch(void* const* d_in, const int* in_sizes, int n_in,
                              void* d_out, int out_size, void* d_ws, size_t ws_size,
                              hipStream_t stream) {
  const float* in = (const float*)d_in[0];
  float* out = (float*)d_out;

  cov_partial<<<dim3(kB * kNFT * kNTC), dim3(256), 0, stream>>>(in, out);

  const int total4 = kB * kS4;
  cov_combine<<<dim3((total4 + 255) / 256), dim3(256), 0, stream>>>((float4*)out);

  const unsigned total4b = (unsigned)kB * kT * kF * (kC / 4);
  cov_bcast<<<dim3((total4b + 255u) / 256u), dim3(256), 0, stream>>>((float4*)out);
}